// Round 2
// baseline (318.644 us; speedup 1.0000x reference)
//
#include <hip/hip_runtime.h>
#include <hip/hip_bf16.h>

#define Qn 2048
#define Kn 2048
#define Cin 128
#define Hn 8
#define CHn 32
#define HDn 256
#define NSPLIT 8

typedef __attribute__((ext_vector_type(8))) short short8;
typedef __attribute__((ext_vector_type(4))) float f32x4;

static __device__ __forceinline__ unsigned short f2bf(float f) {
    unsigned int u = __float_as_uint(f);
    u += 0x7fffu + ((u >> 16) & 1u);
    return (unsigned short)(u >> 16);
}

// ---------------------------------------------------------------------------
// K1: projections. q=(qx@Wq)/sqrt(CH)->bf16 [Q][HD]; k=kvx@Wk->bf16 [K][HD];
//     v=kvx@Wv->bf16 TRANSPOSED [HD][K]; g=sigmoid(qx@Wg+bg)->f32 [Q][HD].
// ---------------------------------------------------------------------------
__global__ __launch_bounds__(256) void proj_kernel(
    const float* __restrict__ qx, const float* __restrict__ kvx,
    const float* __restrict__ Wq, const float* __restrict__ Wk,
    const float* __restrict__ Wv, const float* __restrict__ Wg,
    const float* __restrict__ bg,
    unsigned short* __restrict__ qb, unsigned short* __restrict__ kb,
    unsigned short* __restrict__ vtb, float* __restrict__ gb)
{
    const int mat = blockIdx.y;
    const int r0 = blockIdx.x * 8;
    const int j = threadIdx.x;
    const float* A = (mat == 0 || mat == 3) ? qx : kvx;
    const float* W = (mat == 0) ? Wq : (mat == 1) ? Wk : (mat == 2) ? Wv : Wg;
    const float* Ar = A + r0 * Cin;
    float acc[8] = {0.f, 0.f, 0.f, 0.f, 0.f, 0.f, 0.f, 0.f};
    for (int c = 0; c < Cin; ++c) {
        const float w = W[c * HDn + j];
        #pragma unroll
        for (int i = 0; i < 8; ++i)
            acc[i] = fmaf(Ar[i * Cin + c], w, acc[i]);
    }
    if (mat == 0) {
        const float s = 0.17677669529663687f; // 1/sqrt(32)
        #pragma unroll
        for (int i = 0; i < 8; ++i)
            qb[(r0 + i) * HDn + j] = f2bf(acc[i] * s);
    } else if (mat == 1) {
        #pragma unroll
        for (int i = 0; i < 8; ++i)
            kb[(r0 + i) * HDn + j] = f2bf(acc[i]);
    } else if (mat == 2) {
        unsigned short tmp[8];
        #pragma unroll
        for (int i = 0; i < 8; ++i) tmp[i] = f2bf(acc[i]);
        *(short8*)(vtb + (size_t)j * Kn + r0) = *(short8*)tmp;
    } else {
        const float b = bg[j];
        #pragma unroll
        for (int i = 0; i < 8; ++i)
            gb[(r0 + i) * HDn + j] = 1.f / (1.f + __expf(-(acc[i] + b)));
    }
}

// ---------------------------------------------------------------------------
// K2: fused attention. Grid 1024 = 128 q-tiles x 8 K-splits, 512 thr = 8 waves
// (wave == head).
//
// THIS ROUND: the dist/bias LDS staging (and BOTH per-tile block barriers) are
// deleted. Each lane loads its 16 dist/bias values directly from global with
// per-lane dword gathers in the exact MFMA C-layout it consumes them in:
//   dist[((q0+g*4+r)*Kn + k0+kkg*16+n)*8 + h],  bias[(q0+g*4+r)*Kn + k0+kkg*16+n]
// Within a block every 64B dist line (2 k x 8 h) is fully consumed by the 8
// head-waves, so HBM-granularity traffic is unchanged; L1/L2 serve the
// intra-block sharing. Waves are now fully independent (no __syncthreads at
// all) — 16 free-running waves/CU hide the gather latency via TLP.
// vmcnt discipline per tile: issue kf(4) -> vf(4) -> db(16) -> bb(16);
// QK waits vmcnt(36) (kf only), PV waits vmcnt(32) (vf), exp drains db/bb
// with QK in between as cover. No-max softmax safe: |logit| < 8.
// ---------------------------------------------------------------------------
__global__ __launch_bounds__(512, 4) void attn_kernel(
    const unsigned short* __restrict__ qb, const unsigned short* __restrict__ kb,
    const unsigned short* __restrict__ vtb,
    const float* __restrict__ bias, const float* __restrict__ dist,
    float* __restrict__ opart, float* __restrict__ lpart)
{
    __shared__ unsigned short ps[Hn][16][72]; // P round-trip, wave-local (18432 B)

    const int bx = blockIdx.x;
    const int qt = bx >> 3;
    const int sp = bx & 7;
    const int q0 = qt * 16;
    const int k00 = sp * 256;
    const int t = threadIdx.x;
    const int h = t >> 6;
    const int l = t & 63;
    const int g = l >> 4;
    const int n = l & 15;

    const short8 qf = *(const short8*)(qb + (q0 + n) * HDn + h * CHn + g * 8);

    f32x4 o0 = {0.f, 0.f, 0.f, 0.f};
    f32x4 o1 = {0.f, 0.f, 0.f, 0.f};
    float lacc[4] = {0.f, 0.f, 0.f, 0.f};
    unsigned short* psh = &ps[h][0][0];
    const f32x4 z = {0.f, 0.f, 0.f, 0.f};

    // per-lane base pointers for the scatter gathers (row q0+g*4, col k00+n)
    const float* dbase = dist + ((size_t)(q0 + g * 4) * Kn + k00 + n) * Hn + h;
    const float* bbase = bias + (size_t)(q0 + g * 4) * Kn + k00 + n;

    #pragma unroll
    for (int kt = 0; kt < 4; ++kt) {
        const int k0 = k00 + kt * 64;

        // L2-hot K/V fragments FIRST (oldest in vmcnt order)
        short8 kf[4];
        #pragma unroll
        for (int kkg = 0; kkg < 4; ++kkg)
            kf[kkg] = *(const short8*)(kb + (k0 + kkg * 16 + n) * HDn + h * CHn + g * 8);
        short8 vf[4];
        #pragma unroll
        for (int chunk = 0; chunk < 2; ++chunk) {
            vf[chunk * 2]     = *(const short8*)(vtb + (h * CHn + n) * Kn + k0 + chunk * 32 + g * 8);
            vf[chunk * 2 + 1] = *(const short8*)(vtb + (h * CHn + 16 + n) * Kn + k0 + chunk * 32 + g * 8);
        }
        __builtin_amdgcn_sched_barrier(0); // pin: kf/vf issue before the gathers

        // per-lane dist/bias gathers, MFMA C-layout
        float db[16], bb[16];
        #pragma unroll
        for (int r = 0; r < 4; ++r) {
            #pragma unroll
            for (int kk = 0; kk < 4; ++kk) {
                db[r * 4 + kk] = dbase[((size_t)r * Kn + kt * 64 + kk * 16) * Hn];
                bb[r * 4 + kk] = bbase[(size_t)r * Kn + kt * 64 + kk * 16];
            }
        }

        // QK^T (waits kf only: vmcnt leaves vf + gathers outstanding)
        f32x4 sf[4];
        #pragma unroll
        for (int kkg = 0; kkg < 4; ++kkg)
            sf[kkg] = __builtin_amdgcn_mfma_f32_16x16x32_bf16(qf, kf[kkg], z, 0, 0, 0);

        // p = exp(s + dist + bias); accumulate row sums per-lane
        #pragma unroll
        for (int kkg = 0; kkg < 4; ++kkg) {
            #pragma unroll
            for (int r = 0; r < 4; ++r) {
                const float p = __expf(sf[kkg][r] + db[r * 4 + kkg] + bb[r * 4 + kkg]);
                sf[kkg][r] = p;
                lacc[r] += p;
            }
        }

        // P: D-layout -> LDS bf16 (wave-local; lgkm wait only, no barrier)
        #pragma unroll
        for (int kkg = 0; kkg < 4; ++kkg) {
            #pragma unroll
            for (int r = 0; r < 4; ++r)
                psh[(g * 4 + r) * 72 + kkg * 16 + n] = f2bf(sf[kkg][r]);
        }

        // PV (waits vf; nothing younger needed)
        #pragma unroll
        for (int chunk = 0; chunk < 2; ++chunk) {
            const short8 pf = *(const short8*)(psh + n * 72 + chunk * 32 + g * 8);
            o0 = __builtin_amdgcn_mfma_f32_16x16x32_bf16(pf, vf[chunk * 2], o0, 0, 0, 0);
            o1 = __builtin_amdgcn_mfma_f32_16x16x32_bf16(pf, vf[chunk * 2 + 1], o1, 0, 0, 0);
        }
    }

    // write partial O and row-sums
    float* op = opart + (size_t)sp * (Qn * HDn);
    #pragma unroll
    for (int r = 0; r < 4; ++r) {
        const int qg = q0 + g * 4 + r;
        op[qg * HDn + h * CHn + n] = o0[r];
        op[qg * HDn + h * CHn + 16 + n] = o1[r];
        float v = lacc[r];
        v += __shfl_xor(v, 1);
        v += __shfl_xor(v, 2);
        v += __shfl_xor(v, 4);
        v += __shfl_xor(v, 8);
        lacc[r] = v;
    }
    if (n == 0) {
        float* lp = lpart + (size_t)sp * (Qn * Hn);
        #pragma unroll
        for (int r = 0; r < 4; ++r)
            lp[(q0 + g * 4 + r) * Hn + h] = lacc[r];
    }
}

// ---------------------------------------------------------------------------
// K3: merge splits + gating + output projection. One block per q-row.
// ---------------------------------------------------------------------------
__global__ __launch_bounds__(256) void mergeout_kernel(
    const float* __restrict__ opart, const float* __restrict__ lpart,
    const float* __restrict__ gb, const float* __restrict__ Wo,
    const float* __restrict__ bo, float* __restrict__ out)
{
    __shared__ float olds[HDn];
    __shared__ float red[4][128];
    const int q = blockIdx.x;
    const int t = threadIdx.x;
    const int h = t >> 5;
    float s = 0.f;
    #pragma unroll
    for (int sp = 0; sp < NSPLIT; ++sp)
        s += opart[(size_t)sp * (Qn * HDn) + q * HDn + t];
    float lt = 0.f;
    #pragma unroll
    for (int sp = 0; sp < NSPLIT; ++sp)
        lt += lpart[(size_t)sp * (Qn * Hn) + q * Hn + h];
    olds[t] = (s / lt) * gb[q * HDn + t];
    __syncthreads();
    const int p = t & 63;
    const int seg = t >> 6;
    float a0 = 0.f, a1 = 0.f;
    for (int c = seg * 64; c < seg * 64 + 64; ++c) {
        const float ov = olds[c];
        const float2 w = *(const float2*)(Wo + c * Cin + 2 * p);
        a0 = fmaf(ov, w.x, a0);
        a1 = fmaf(ov, w.y, a1);
    }
    red[seg][2 * p] = a0;
    red[seg][2 * p + 1] = a1;
    __syncthreads();
    if (t < 128)
        out[q * Cin + t] = red[0][t] + red[1][t] + red[2][t] + red[3][t] + bo[t];
}

extern "C" void kernel_launch(void* const* d_in, const int* in_sizes, int n_in,
                              void* d_out, int out_size, void* d_ws, size_t ws_size,
                              hipStream_t stream)
{
    const float* qx   = (const float*)d_in[0];
    const float* kvx  = (const float*)d_in[1];
    const float* bias = (const float*)d_in[2];
    const float* dist = (const float*)d_in[3];
    const float* Wq   = (const float*)d_in[4];
    const float* Wk   = (const float*)d_in[5];
    const float* Wv   = (const float*)d_in[6];
    const float* Wg   = (const float*)d_in[7];
    const float* bg   = (const float*)d_in[8];
    const float* Wo   = (const float*)d_in[9];
    const float* bo   = (const float*)d_in[10];
    float* out = (float*)d_out;

    char* w = (char*)d_ws;
    unsigned short* qb  = (unsigned short*)(w);                  // 1 MB
    unsigned short* kb  = (unsigned short*)(w + (1ull << 20));   // 1 MB
    unsigned short* vtb = (unsigned short*)(w + (2ull << 20));   // 1 MB
    float* gb    = (float*)(w + (3ull << 20));                   // 2 MB
    float* opart = (float*)(w + (5ull << 20));                   // 16 MB (8 splits)
    float* lpart = (float*)(w + (21ull << 20));                  // 512 KB

    proj_kernel<<<dim3(Qn / 8, 4), 256, 0, stream>>>(qx, kvx, Wq, Wk, Wv, Wg, bg, qb, kb, vtb, gb);
    attn_kernel<<<dim3(128 * NSPLIT), 512, 0, stream>>>(qb, kb, vtb, bias, dist, opart, lpart);
    mergeout_kernel<<<dim3(Qn), 256, 0, stream>>>(opart, lpart, gb, Wo, bo, out);
}

// Round 3
// 279.104 us; speedup vs baseline: 1.1417x; 1.1417x over previous
//
#include <hip/hip_runtime.h>
#include <hip/hip_bf16.h>

#define Qn 2048
#define Kn 2048
#define Cin 128
#define Hn 8
#define CHn 32
#define HDn 256
#define NSPLIT 8

typedef __attribute__((ext_vector_type(8))) short short8;
typedef __attribute__((ext_vector_type(4))) float f32x4;

static __device__ __forceinline__ unsigned short f2bf(float f) {
    unsigned int u = __float_as_uint(f);
    u += 0x7fffu + ((u >> 16) & 1u);
    return (unsigned short)(u >> 16);
}

// async 16B global->LDS (gfx950). Global src is PER-LANE; LDS dst is
// wave-uniform base + lane*16.
static __device__ __forceinline__ void ld16(const void* g, void* l) {
    __builtin_amdgcn_global_load_lds(
        (const __attribute__((address_space(1))) void*)g,
        (__attribute__((address_space(3))) void*)l, 16, 0, 0);
}

// ---------------------------------------------------------------------------
// K1: projections. q=(qx@Wq)/sqrt(CH)->bf16 [Q][HD]; k=kvx@Wk->bf16 [K][HD];
//     v=kvx@Wv->bf16 TRANSPOSED [HD][K]; g=sigmoid(qx@Wg+bg)->f32 [Q][HD].
// ---------------------------------------------------------------------------
__global__ __launch_bounds__(256) void proj_kernel(
    const float* __restrict__ qx, const float* __restrict__ kvx,
    const float* __restrict__ Wq, const float* __restrict__ Wk,
    const float* __restrict__ Wv, const float* __restrict__ Wg,
    const float* __restrict__ bg,
    unsigned short* __restrict__ qb, unsigned short* __restrict__ kb,
    unsigned short* __restrict__ vtb, float* __restrict__ gb)
{
    const int mat = blockIdx.y;
    const int r0 = blockIdx.x * 8;
    const int j = threadIdx.x;
    const float* A = (mat == 0 || mat == 3) ? qx : kvx;
    const float* W = (mat == 0) ? Wq : (mat == 1) ? Wk : (mat == 2) ? Wv : Wg;
    const float* Ar = A + r0 * Cin;
    float acc[8] = {0.f, 0.f, 0.f, 0.f, 0.f, 0.f, 0.f, 0.f};
    for (int c = 0; c < Cin; ++c) {
        const float w = W[c * HDn + j];
        #pragma unroll
        for (int i = 0; i < 8; ++i)
            acc[i] = fmaf(Ar[i * Cin + c], w, acc[i]);
    }
    if (mat == 0) {
        const float s = 0.17677669529663687f; // 1/sqrt(32)
        #pragma unroll
        for (int i = 0; i < 8; ++i)
            qb[(r0 + i) * HDn + j] = f2bf(acc[i] * s);
    } else if (mat == 1) {
        #pragma unroll
        for (int i = 0; i < 8; ++i)
            kb[(r0 + i) * HDn + j] = f2bf(acc[i]);
    } else if (mat == 2) {
        unsigned short tmp[8];
        #pragma unroll
        for (int i = 0; i < 8; ++i) tmp[i] = f2bf(acc[i]);
        *(short8*)(vtb + (size_t)j * Kn + r0) = *(short8*)tmp;
    } else {
        const float b = bg[j];
        #pragma unroll
        for (int i = 0; i < 8; ++i)
            gb[(r0 + i) * HDn + j] = 1.f / (1.f + __expf(-(acc[i] + b)));
    }
}

// ---------------------------------------------------------------------------
// K2: fused attention. Grid 1024 = 128 q-tiles x 8 K-splits, 512 thr = 8 waves
// (wave == head). KVBLK=32, 8 tiles/block.
//
// THIS ROUND (Little's-law fix): dist+bias staged as f32 DIRECTLY into LDS via
// global_load_lds (double-buffered). In-flight bytes live in the VMEM queue
// (full ~18KB next-tile prefetch per block) instead of 80 B/wave of registers,
// lifting the outstanding-bytes cap from ~1.2 TB/s to fabric-class BW.
// Sync: ONE {vmcnt(0); s_barrier} per tile — the only outstanding VMEM at the
// drain is the prefetched tile itself (+ L2-hot K/V reg-prefetch, retired for
// free). K/V fragments are register-prefetched one tile ahead, so QK/PV need
// no waits. dist LDS reads are 4-way bank-conflicted (linear load_lds layout,
// can't pad) — accepted, ~8 b32 reads/lane/tile. No-max softmax: |logit| < 8.
// ---------------------------------------------------------------------------
__global__ __launch_bounds__(512, 4) void attn_kernel(
    const unsigned short* __restrict__ qb, const unsigned short* __restrict__ kb,
    const unsigned short* __restrict__ vtb,
    const float* __restrict__ bias, const float* __restrict__ dist,
    float* __restrict__ opart, float* __restrict__ lpart)
{
    __shared__ float dlds[2][16][32][8];      // 32 KB  [buf][q][k][h]
    __shared__ float blds[2][16][32];         // 4 KB   [buf][q][k]
    __shared__ unsigned short ps[Hn][16][40]; // 10.25 KB, P round-trip

    const int bx = blockIdx.x;
    const int qt = bx >> 3;
    const int sp = bx & 7;
    const int q0 = qt * 16;
    const int k00 = sp * 256;
    const int t = threadIdx.x;
    const int h = t >> 6;   // wave id == head
    const int l = t & 63;
    const int g = l >> 4;
    const int n = l & 15;

    const short8 qf = *(const short8*)(qb + (q0 + n) * HDn + h * CHn + g * 8);

    f32x4 o0 = {0.f, 0.f, 0.f, 0.f};
    f32x4 o1 = {0.f, 0.f, 0.f, 0.f};
    float lacc[4] = {0.f, 0.f, 0.f, 0.f};
    unsigned short* psh = &ps[h][0][0];
    const f32x4 z = {0.f, 0.f, 0.f, 0.f};

    // per-lane staging sources. dist row segment [k0,k0+32) x 8h = 256 floats
    // contiguous; lane l covers floats l*4..l*4+3. bias: lane l covers
    // (q = h*8 + (l>>3), k = (l&7)*4..+3).
    const float* dsrcA = dist + (size_t)(q0 + h) * Kn * Hn + l * 4;
    const float* dsrcB = dist + (size_t)(q0 + h + 8) * Kn * Hn + l * 4;
    const float* bsrc  = bias + (size_t)(q0 + h * 8 + (l >> 3)) * Kn + (l & 7) * 4;

    short8 kf[2][2], vf[2][2];

    #define STAGE(buf, kt_) do {                                              \
        const int k0s = k00 + (kt_) * 32;                                     \
        ld16(dsrcA + (size_t)k0s * 8, &dlds[buf][h][0][0]);                   \
        ld16(dsrcB + (size_t)k0s * 8, &dlds[buf][h + 8][0][0]);               \
        if (h < 2) ld16(bsrc + k0s, &blds[buf][h * 8][0]);                    \
    } while (0)

    #define KVLOAD(set, kt_) do {                                             \
        const int k0v = k00 + (kt_) * 32;                                     \
        kf[set][0] = *(const short8*)(kb + (k0v + n) * HDn + h * CHn + g * 8);      \
        kf[set][1] = *(const short8*)(kb + (k0v + 16 + n) * HDn + h * CHn + g * 8); \
        vf[set][0] = *(const short8*)(vtb + (h * CHn + n) * Kn + k0v + g * 8);      \
        vf[set][1] = *(const short8*)(vtb + (h * CHn + 16 + n) * Kn + k0v + g * 8); \
    } while (0)

    // prologue: K/V regs + LDS stage for tile 0
    KVLOAD(0, 0);
    __builtin_amdgcn_sched_barrier(0);
    STAGE(0, 0);

    #pragma unroll
    for (int kt = 0; kt < 8; ++kt) {
        const int cur = kt & 1;
        // drain this tile's stage (and last tile's K/V regs) + block barrier.
        // Compiler-tracked waits after this are trivially satisfied.
        asm volatile("s_waitcnt vmcnt(0)\n\ts_barrier" ::: "memory");
        if (kt < 7) {
            KVLOAD(cur ^ 1, kt + 1);
            __builtin_amdgcn_sched_barrier(0);
            STAGE(cur ^ 1, kt + 1);
            __builtin_amdgcn_sched_barrier(0);
        }
        // QK^T (kf issued >=1 tile ago: wait-free)
        f32x4 sf[2];
        sf[0] = __builtin_amdgcn_mfma_f32_16x16x32_bf16(qf, kf[cur][0], z, 0, 0, 0);
        sf[1] = __builtin_amdgcn_mfma_f32_16x16x32_bf16(qf, kf[cur][1], z, 0, 0, 0);
        // p = exp(s + dist + bias) from LDS; row sums; P -> LDS bf16
        #pragma unroll
        for (int kk = 0; kk < 2; ++kk) {
            #pragma unroll
            for (int r = 0; r < 4; ++r) {
                const float p = __expf(sf[kk][r]
                                       + dlds[cur][g * 4 + r][kk * 16 + n][h]
                                       + blds[cur][g * 4 + r][kk * 16 + n]);
                sf[kk][r] = p;
                lacc[r] += p;
                psh[(g * 4 + r) * 40 + kk * 16 + n] = f2bf(p);
            }
        }
        // PV (vf issued >=1 tile ago: wait-free)
        const short8 pf = *(const short8*)(psh + n * 40 + g * 8);
        o0 = __builtin_amdgcn_mfma_f32_16x16x32_bf16(pf, vf[cur][0], o0, 0, 0, 0);
        o1 = __builtin_amdgcn_mfma_f32_16x16x32_bf16(pf, vf[cur][1], o1, 0, 0, 0);
    }
    #undef STAGE
    #undef KVLOAD

    // write partial O and row-sums
    float* op = opart + (size_t)sp * (Qn * HDn);
    #pragma unroll
    for (int r = 0; r < 4; ++r) {
        const int qg = q0 + g * 4 + r;
        op[qg * HDn + h * CHn + n] = o0[r];
        op[qg * HDn + h * CHn + 16 + n] = o1[r];
        float v = lacc[r];
        v += __shfl_xor(v, 1);
        v += __shfl_xor(v, 2);
        v += __shfl_xor(v, 4);
        v += __shfl_xor(v, 8);
        lacc[r] = v;
    }
    if (n == 0) {
        float* lp = lpart + (size_t)sp * (Qn * Hn);
        #pragma unroll
        for (int r = 0; r < 4; ++r)
            lp[(q0 + g * 4 + r) * Hn + h] = lacc[r];
    }
}

// ---------------------------------------------------------------------------
// K3: merge splits + gating + output projection. One block per q-row.
// ---------------------------------------------------------------------------
__global__ __launch_bounds__(256) void mergeout_kernel(
    const float* __restrict__ opart, const float* __restrict__ lpart,
    const float* __restrict__ gb, const float* __restrict__ Wo,
    const float* __restrict__ bo, float* __restrict__ out)
{
    __shared__ float olds[HDn];
    __shared__ float red[4][128];
    const int q = blockIdx.x;
    const int t = threadIdx.x;
    const int h = t >> 5;
    float s = 0.f;
    #pragma unroll
    for (int sp = 0; sp < NSPLIT; ++sp)
        s += opart[(size_t)sp * (Qn * HDn) + q * HDn + t];
    float lt = 0.f;
    #pragma unroll
    for (int sp = 0; sp < NSPLIT; ++sp)
        lt += lpart[(size_t)sp * (Qn * Hn) + q * Hn + h];
    olds[t] = (s / lt) * gb[q * HDn + t];
    __syncthreads();
    const int p = t & 63;
    const int seg = t >> 6;
    float a0 = 0.f, a1 = 0.f;
    for (int c = seg * 64; c < seg * 64 + 64; ++c) {
        const float ov = olds[c];
        const float2 w = *(const float2*)(Wo + c * Cin + 2 * p);
        a0 = fmaf(ov, w.x, a0);
        a1 = fmaf(ov, w.y, a1);
    }
    red[seg][2 * p] = a0;
    red[seg][2 * p + 1] = a1;
    __syncthreads();
    if (t < 128)
        out[q * Cin + t] = red[0][t] + red[1][t] + red[2][t] + red[3][t] + bo[t];
}

extern "C" void kernel_launch(void* const* d_in, const int* in_sizes, int n_in,
                              void* d_out, int out_size, void* d_ws, size_t ws_size,
                              hipStream_t stream)
{
    const float* qx   = (const float*)d_in[0];
    const float* kvx  = (const float*)d_in[1];
    const float* bias = (const float*)d_in[2];
    const float* dist = (const float*)d_in[3];
    const float* Wq   = (const float*)d_in[4];
    const float* Wk   = (const float*)d_in[5];
    const float* Wv   = (const float*)d_in[6];
    const float* Wg   = (const float*)d_in[7];
    const float* bg   = (const float*)d_in[8];
    const float* Wo   = (const float*)d_in[9];
    const float* bo   = (const float*)d_in[10];
    float* out = (float*)d_out;

    char* w = (char*)d_ws;
    unsigned short* qb  = (unsigned short*)(w);                  // 1 MB
    unsigned short* kb  = (unsigned short*)(w + (1ull << 20));   // 1 MB
    unsigned short* vtb = (unsigned short*)(w + (2ull << 20));   // 1 MB
    float* gb    = (float*)(w + (3ull << 20));                   // 2 MB
    float* opart = (float*)(w + (5ull << 20));                   // 16 MB (8 splits)
    float* lpart = (float*)(w + (21ull << 20));                  // 512 KB

    proj_kernel<<<dim3(Qn / 8, 4), 256, 0, stream>>>(qx, kvx, Wq, Wk, Wv, Wg, bg, qb, kb, vtb, gb);
    attn_kernel<<<dim3(128 * NSPLIT), 512, 0, stream>>>(qb, kb, vtb, bias, dist, opart, lpart);
    mergeout_kernel<<<dim3(Qn), 256, 0, stream>>>(opart, lpart, gb, Wo, bo, out);
}